// Round 11
// baseline (289.272 us; speedup 1.0000x reference)
//
#include <hip/hip_runtime.h>
#include <hip/hip_fp16.h>

#define N_NODES 50000
#define N_EDGES 1600000
#define FIN 256
#define HD 128          // HEADS*HIDDEN
#define NHEADS 4
#define C2 16           // NUM_CLASSES
#define NEG 0.2f

// bucketed counting-sort CSR build
#define EBLK 4096
#define NBLK 391        // ceil(N_EDGES/EBLK)
#define NBUCK 391       // ceil(N_NODES/128)
#define BSH 7
#define BMASK 127
#define MAXB 5120       // bucket capacity: mean 4096, sigma ~64 -> +16 sigma

typedef _Float16 v8h __attribute__((ext_vector_type(8)));
typedef float v4f __attribute__((ext_vector_type(4)));
union F4H8 { float4 f; v8h h; };

__device__ __forceinline__ float elu1(float x) { return x > 0.f ? x : __expf(x) - 1.f; }
__device__ __forceinline__ float lexp(float e) { return __expf(e > 0.f ? e : NEG * e); }

// ---------------- CSR build: bucketed counting sort ----------------

__global__ __launch_bounds__(256) void k_bhist(const int* __restrict__ dst,
                                               int* __restrict__ ghist) {
    __shared__ int lh[NBUCK];
    int tid = threadIdx.x, b = blockIdx.x;
    for (int t = tid; t < NBUCK; t += 256) lh[t] = 0;
    __syncthreads();
    int base = b * EBLK;
    int nq = (min(EBLK, N_EDGES - base)) >> 2;
    const int4* d4 = (const int4*)(dst + base);
    for (int q = tid; q < nq; q += 256) {
        int4 d = d4[q];
        atomicAdd(&lh[d.x >> BSH], 1);
        atomicAdd(&lh[d.y >> BSH], 1);
        atomicAdd(&lh[d.z >> BSH], 1);
        atomicAdd(&lh[d.w >> BSH], 1);
    }
    __syncthreads();
    for (int t = tid; t < NBUCK; t += 256) ghist[t * NBLK + b] = lh[t];
}

__global__ __launch_bounds__(256) void k_bscan1(int* __restrict__ ghist,
                                                int* __restrict__ bucket_tot) {
    __shared__ int s[256];
    int B = blockIdx.x, t = threadIdx.x;
    int* row = ghist + (size_t)B * NBLK;
    int i0 = 2 * t, i1 = 2 * t + 1;
    int a0 = (i0 < NBLK) ? row[i0] : 0;
    int a1 = (i1 < NBLK) ? row[i1] : 0;
    int pair = a0 + a1;
    s[t] = pair;
    __syncthreads();
    for (int off = 1; off < 256; off <<= 1) {
        int u = (t >= off) ? s[t - off] : 0;
        __syncthreads();
        s[t] += u;
        __syncthreads();
    }
    int excl = s[t] - pair;
    if (i0 < NBLK) row[i0] = excl;
    if (i1 < NBLK) row[i1] = excl + a0;
    if (t == 255) bucket_tot[B] = s[255];
}

__global__ __launch_bounds__(512) void k_bscan2(const int* __restrict__ bucket_tot,
                                                int* __restrict__ bucket_base,
                                                int* __restrict__ rowstart) {
    __shared__ int s[512];
    int t = threadIdx.x;
    int v = (t < NBUCK) ? bucket_tot[t] : 0;
    s[t] = v;
    __syncthreads();
    for (int off = 1; off < 512; off <<= 1) {
        int u = (t >= off) ? s[t - off] : 0;
        __syncthreads();
        s[t] += u;
        __syncthreads();
    }
    if (t < NBUCK) bucket_base[t] = s[t] - v;
    if (t == 0) { bucket_base[NBUCK] = N_EDGES; rowstart[N_NODES] = N_EDGES; }
}

__global__ __launch_bounds__(256) void k_bscatter(
        const int* __restrict__ src, const int* __restrict__ dst,
        const int* __restrict__ ghist, const int* __restrict__ bucket_base,
        int* __restrict__ ebuf) {
    __shared__ int lcur[NBUCK];
    int tid = threadIdx.x, b = blockIdx.x;
    for (int t = tid; t < NBUCK; t += 256)
        lcur[t] = bucket_base[t] + ghist[t * NBLK + b];
    __syncthreads();
    int base = b * EBLK;
    int nq = (min(EBLK, N_EDGES - base)) >> 2;
    const int4* s4 = (const int4*)(src + base);
    const int4* d4 = (const int4*)(dst + base);
    for (int q = tid; q < nq; q += 256) {
        int4 s = s4[q];
        int4 d = d4[q];
        int p;
        p = atomicAdd(&lcur[d.x >> BSH], 1); ebuf[p] = (s.x << BSH) | (d.x & BMASK);
        p = atomicAdd(&lcur[d.y >> BSH], 1); ebuf[p] = (s.y << BSH) | (d.y & BMASK);
        p = atomicAdd(&lcur[d.z >> BSH], 1); ebuf[p] = (s.z << BSH) | (d.z & BMASK);
        p = atomicAdd(&lcur[d.w >> BSH], 1); ebuf[p] = (s.w << BSH) | (d.w & BMASK);
    }
}

__global__ __launch_bounds__(256) void k_bsort(
        const int* __restrict__ ebuf, const int* __restrict__ bucket_base,
        int* __restrict__ sorted_src, int* __restrict__ rowstart) {
    __shared__ int ein[MAXB];
    __shared__ int eout[MAXB];
    __shared__ int hist[128];
    __shared__ int sc[128];
    __shared__ int cursor[128];
    int tid = threadIdx.x, B = blockIdx.x;
    int base = bucket_base[B];
    int n = bucket_base[B + 1] - base;
    if (tid < 128) hist[tid] = 0;
    __syncthreads();
    for (int i = tid; i < n; i += 256) {
        int v = ebuf[base + i];
        ein[i] = v;
        atomicAdd(&hist[v & BMASK], 1);
    }
    __syncthreads();
    if (tid < 128) sc[tid] = hist[tid];
    __syncthreads();
    for (int off = 1; off < 128; off <<= 1) {
        int u = 0;
        if (tid < 128 && tid >= off) u = sc[tid - off];
        __syncthreads();
        if (tid < 128) sc[tid] += u;
        __syncthreads();
    }
    if (tid < 128) {
        int ex = sc[tid] - hist[tid];
        cursor[tid] = ex;
        int node = B * 128 + tid;
        if (node < N_NODES) rowstart[node] = base + ex;
    }
    __syncthreads();
    for (int i = tid; i < n; i += 256) {
        int v = ein[i];
        int p = atomicAdd(&cursor[v & BMASK], 1);
        eout[p] = v >> BSH;
    }
    __syncthreads();
    for (int i = tid; i < n; i += 256) sorted_src[base + i] = eout[i];
}

// ---------------- W1 -> fp16 transposed [col][k] ----------------

__global__ __launch_bounds__(256) void k_w1half(const float* __restrict__ W1,
                                                _Float16* __restrict__ W1T) {
    int idx = blockIdx.x * 256 + threadIdx.x;   // 32768 total
    int k = idx >> 7, c = idx & 127;
    W1T[c * 256 + k] = (_Float16)W1[idx];
}

// ---------------- Layer 1 GEMM via MFMA fp16: feath (head-major) + el1/er1 ----
// feath layout: [head][node][32 cols] fp16 -> 3.2 MB per head slice (L2-resident).

__global__ __launch_bounds__(256) void k_gemm1(
        const float* __restrict__ x, const _Float16* __restrict__ W1T,
        const float* __restrict__ al1, const float* __restrict__ ar1,
        __half* __restrict__ feath, float* __restrict__ el1, float* __restrict__ er1) {
    __shared__ v8h As[64 * 4];    // 64 nodes x 32k fp16, 4 KB
    __shared__ v8h Bs[128 * 4];   // 128 cols x 32k fp16, 8 KB
    int tid = threadIdx.x;
    int nb = blockIdx.x * 64;
    int wid = tid >> 6, lane = tid & 63;
    int wm = wid & 1, wn = wid >> 1;      // wave tile: rows wm*32.., cols wn*64..
    int q = lane >> 4, lm = lane & 15;

    int anode = tid >> 2, ach = tid & 3;
    int gnode = nb + anode; if (gnode >= N_NODES) gnode = N_NODES - 1;
    const float4* xrow = (const float4*)(x + (size_t)gnode * FIN);
    int bc = tid >> 2, bch = tid & 3;

    v4f acc[2][4];
    #pragma unroll
    for (int mt = 0; mt < 2; mt++)
        #pragma unroll
        for (int nt = 0; nt < 4; nt++) acc[mt][nt] = (v4f)(0.f);

    float4 xa0 = xrow[ach * 2];
    float4 xa1 = xrow[ach * 2 + 1];
    F4H8 wb0, wb1;
    wb0.f = *(const float4*)(W1T + bc * 256 + bch * 8);
    wb1.f = *(const float4*)(W1T + (bc + 64) * 256 + bch * 8);

    for (int step = 0; step < 8; step++) {
        __syncthreads();
        {
            v8h av;
            av[0] = (_Float16)xa0.x; av[1] = (_Float16)xa0.y;
            av[2] = (_Float16)xa0.z; av[3] = (_Float16)xa0.w;
            av[4] = (_Float16)xa1.x; av[5] = (_Float16)xa1.y;
            av[6] = (_Float16)xa1.z; av[7] = (_Float16)xa1.w;
            As[anode * 4 + (ach ^ (anode & 3))] = av;
            Bs[bc * 4 + (bch ^ (bc & 3))] = wb0.h;
            Bs[(bc + 64) * 4 + (bch ^ (bc & 3))] = wb1.h;
        }
        __syncthreads();
        if (step < 7) {
            int k0 = (step + 1) * 32;
            xa0 = xrow[(k0 >> 2) + ach * 2];
            xa1 = xrow[(k0 >> 2) + ach * 2 + 1];
            wb0.f = *(const float4*)(W1T + bc * 256 + k0 + bch * 8);
            wb1.f = *(const float4*)(W1T + (bc + 64) * 256 + k0 + bch * 8);
        }
        v8h af[2], bf[4];
        #pragma unroll
        for (int mt = 0; mt < 2; mt++) {
            int nl = wm * 32 + mt * 16 + lm;
            af[mt] = As[nl * 4 + (q ^ (nl & 3))];
        }
        #pragma unroll
        for (int nt = 0; nt < 4; nt++) {
            int cl = wn * 64 + nt * 16 + lm;
            bf[nt] = Bs[cl * 4 + (q ^ (cl & 3))];
        }
        #pragma unroll
        for (int mt = 0; mt < 2; mt++)
            #pragma unroll
            for (int nt = 0; nt < 4; nt++)
                acc[mt][nt] = __builtin_amdgcn_mfma_f32_16x16x32_f16(
                    af[mt], bf[nt], acc[mt][nt], 0, 0, 0);
    }

    // epilogue: head-major feath stores + fused el/er.
    float alv[4], arv[4];
    #pragma unroll
    for (int nt = 0; nt < 4; nt++) {
        alv[nt] = al1[wn * 64 + nt * 16 + lm];
        arv[nt] = ar1[wn * 64 + nt * 16 + lm];
    }
    int h0 = 2 * wn, h1 = 2 * wn + 1;
    #pragma unroll
    for (int mt = 0; mt < 2; mt++) {
        #pragma unroll
        for (int r = 0; r < 4; r++) {
            int node = nb + wm * 32 + mt * 16 + q * 4 + r;
            bool ok = node < N_NODES;
            float v0 = acc[mt][0][r], v1 = acc[mt][1][r];
            float v2 = acc[mt][2][r], v3 = acc[mt][3][r];
            if (ok) {
                __half* fp0 = feath + ((size_t)h0 * N_NODES + node) * 32 + lm;
                __half* fp1 = feath + ((size_t)h1 * N_NODES + node) * 32 + lm;
                fp0[0]  = __float2half(v0);   // col lm       of head h0
                fp0[16] = __float2half(v1);   // col 16+lm    of head h0
                fp1[0]  = __float2half(v2);   // col lm       of head h1
                fp1[16] = __float2half(v3);   // col 16+lm    of head h1
            }
            float pl0 = v0 * alv[0] + v1 * alv[1];
            float pr0 = v0 * arv[0] + v1 * arv[1];
            float pl1 = v2 * alv[2] + v3 * alv[3];
            float pr1 = v2 * arv[2] + v3 * arv[3];
            #pragma unroll
            for (int m = 1; m <= 8; m <<= 1) {
                pl0 += __shfl_xor(pl0, m); pr0 += __shfl_xor(pr0, m);
                pl1 += __shfl_xor(pl1, m); pr1 += __shfl_xor(pr1, m);
            }
            if (ok && lm == 0) {
                el1[node * 4 + h0] = pl0; er1[node * 4 + h0] = pr0;
                el1[node * 4 + h1] = pl1; er1[node * 4 + h1] = pr1;
            }
        }
    }
}

// ---------------- Layer 1 aggregation: wave per (dst, head), head varies slowest ----
// Per head the gather table is 3.2 MB -> XCD-L2 resident while that head's
// blocks are in flight. Each edge-gather = one 64 B line.

__global__ __launch_bounds__(256) void k_agg1(
        const int* __restrict__ rowstart, const int* __restrict__ sorted_src,
        const float* __restrict__ el1, const float* __restrict__ er1,
        const __half* __restrict__ feath, const float* __restrict__ b1,
        float* __restrict__ h) {
    int p = blockIdx.x * 4 + (threadIdx.x >> 6);   // pair index, head = p / N
    int head = p / N_NODES;
    int d = p - head * N_NODES;
    int lane = threadIdx.x & 63;
    int eg = lane >> 2;                    // edge group 0..15
    int cq = lane & 3;                     // col quad: cols 8cq..8cq+7
    float er = er1[d * 4 + head];
    int start = rowstart[d], end = rowstart[d + 1];
    const float4* fb = (const float4*)feath + (size_t)head * N_NODES * 4;
    float acc[8];
    #pragma unroll
    for (int k = 0; k < 8; k++) acc[k] = 0.f;
    float wsum = 0.f;

    for (int i = start; i < end; i += 32) {
        int s[2]; bool ok[2];
        #pragma unroll
        for (int u = 0; u < 2; u++) {
            int e = i + 16 * u + eg;
            ok[u] = e < end;
            int ec = ok[u] ? e : end - 1;
            s[u] = sorted_src[ec];
        }
        float elv[2];
        #pragma unroll
        for (int u = 0; u < 2; u++) elv[u] = el1[s[u] * 4 + head];
        float4 r[2];
        #pragma unroll
        for (int u = 0; u < 2; u++) r[u] = fb[(size_t)s[u] * 4 + cq];
        #pragma unroll
        for (int u = 0; u < 2; u++) {
            float w = ok[u] ? lexp(elv[u] + er) : 0.f;
            const __half2* ph = (const __half2*)&r[u];
            #pragma unroll
            for (int q = 0; q < 4; q++) {
                float2 f = __half22float2(ph[q]);
                acc[2 * q]     += w * f.x;
                acc[2 * q + 1] += w * f.y;
            }
            wsum += w;
        }
    }
    // reduce across the 16 edge-groups (lane bits 2..5)
    #pragma unroll
    for (int k = 0; k < 8; k++) {
        acc[k] += __shfl_xor(acc[k], 4);
        acc[k] += __shfl_xor(acc[k], 8);
        acc[k] += __shfl_xor(acc[k], 16);
        acc[k] += __shfl_xor(acc[k], 32);
    }
    wsum += __shfl_xor(wsum, 4);
    wsum += __shfl_xor(wsum, 8);
    wsum += __shfl_xor(wsum, 16);
    wsum += __shfl_xor(wsum, 32);
    if (eg == 0) {
        float inv = 1.f / fmaxf(wsum, 1e-9f);
        float v[8];
        #pragma unroll
        for (int k = 0; k < 8; k++)
            v[k] = elu1(acc[k] * inv + b1[head * 32 + cq * 8 + k]);
        float4* hp = (float4*)(h + (size_t)d * HD + head * 32 + cq * 8);
        hp[0] = make_float4(v[0], v[1], v[2], v[3]);
        hp[1] = make_float4(v[4], v[5], v[6], v[7]);
    }
}

// ---------------- Layer 2 GEMM: feat2 = h @ W2, fused el2/er2 ----------------

__global__ __launch_bounds__(256) void k_gemm2(
        const float* __restrict__ h, const float* __restrict__ W2,
        const float* __restrict__ al2, const float* __restrict__ ar2,
        float* __restrict__ feat2, float* __restrict__ el2, float* __restrict__ er2) {
    __shared__ float hs[16 * 132];
    __shared__ float w2t[16 * 132];
    int tid = threadIdx.x;
    int nb = blockIdx.x * 16;  // 50000 % 16 == 0
    for (int idx = tid; idx < 512; idx += 256) {
        int row = idx >> 5, kk = idx & 31;
        ((float4*)(hs + row * 132))[kk] = ((const float4*)h)[(size_t)(nb + row) * 32 + kk];
    }
    for (int idx = tid; idx < 2048; idx += 256) {
        int k = idx >> 4, c = idx & 15;
        w2t[c * 132 + k] = W2[idx];
    }
    __syncthreads();
    int nl = tid >> 4, col = tid & 15;
    const float4* hv = (const float4*)(hs + nl * 132);
    const float4* wv = (const float4*)(w2t + col * 132);
    float acc = 0.f;
    #pragma unroll
    for (int kk = 0; kk < 32; kk++) {
        float4 a = hv[kk], w = wv[kk];
        acc += a.x * w.x + a.y * w.y + a.z * w.z + a.w * w.w;
    }
    int node = nb + nl;
    feat2[node * 16 + col] = acc;
    float pl = acc * al2[col], pr = acc * ar2[col];
    #pragma unroll
    for (int m = 8; m >= 1; m >>= 1) {
        pl += __shfl_xor(pl, m);
        pr += __shfl_xor(pr, m);
    }
    if (col == 0) { el2[node] = pl; er2[node] = pr; }
}

// ---------------- Layer 2 aggregation: wave per dst, 16 edges x 4 col-lanes ----------------

__global__ __launch_bounds__(256) void k_agg2(
        const int* __restrict__ rowstart, const int* __restrict__ sorted_src,
        const float* __restrict__ el2, const float* __restrict__ er2,
        const float* __restrict__ feat2, const float* __restrict__ b2,
        float* __restrict__ out) {
    int tid = threadIdx.x;
    int d = blockIdx.x * 4 + (tid >> 6);   // 50000 % 4 == 0
    int lane = tid & 63;
    int eg = lane >> 2;                    // edge group 0..15
    int cq = lane & 3;                     // cols 4*cq..4*cq+3
    float er = er2[d];
    int start = rowstart[d], end = rowstart[d + 1];
    float4 acc = make_float4(0.f, 0.f, 0.f, 0.f);
    float wsum = 0.f;
    for (int i = start; i < end; i += 16) {
        int e = i + eg;
        bool ok = e < end;
        int ec = ok ? e : end - 1;
        int s = sorted_src[ec];
        float elv = el2[s];
        float4 f = ((const float4*)feat2)[(size_t)s * 4 + cq];
        float ev = elv + er;
        float wr = __expf(ev > 0.f ? ev : NEG * ev);
        float w = ok ? wr : 0.f;
        acc.x += w * f.x; acc.y += w * f.y; acc.z += w * f.z; acc.w += w * f.w;
        wsum += w;
    }
    #pragma unroll
    for (int m = 4; m <= 32; m <<= 1) {
        acc.x += __shfl_xor(acc.x, m);
        acc.y += __shfl_xor(acc.y, m);
        acc.z += __shfl_xor(acc.z, m);
        acc.w += __shfl_xor(acc.w, m);
        wsum  += __shfl_xor(wsum, m);
    }
    if (lane < 4) {
        float inv = 1.f / fmaxf(wsum, 1e-9f);
        float4 bv = ((const float4*)b2)[cq];
        float4 o = make_float4(acc.x * inv + bv.x, acc.y * inv + bv.y,
                               acc.z * inv + bv.z, acc.w * inv + bv.w);
        ((float4*)out)[(size_t)d * 4 + cq] = o;
    }
}

// ---------------- launch ----------------

extern "C" void kernel_launch(void* const* d_in, const int* in_sizes, int n_in,
                              void* d_out, int out_size, void* d_ws, size_t ws_size,
                              hipStream_t stream) {
    const float* x   = (const float*)d_in[0];
    const int*   src = (const int*)d_in[1];
    const int*   dst = (const int*)d_in[2];
    const float* W1  = (const float*)d_in[3];
    const float* b1  = (const float*)d_in[4];
    const float* al1 = (const float*)d_in[5];
    const float* ar1 = (const float*)d_in[6];
    const float* W2  = (const float*)d_in[7];
    const float* b2  = (const float*)d_in[8];
    const float* al2 = (const float*)d_in[9];
    const float* ar2 = (const float*)d_in[10];
    float* out = (float*)d_out;

    char* ws = (char*)d_ws;
    size_t off = 0;
    auto alloc = [&](size_t bytes) -> char* {
        char* p = ws + off;
        off += (bytes + 255) & ~(size_t)255;
        return p;
    };
    __half* feath      = (__half*)alloc((size_t)N_NODES * HD * 2);
    _Float16* W1T      = (_Float16*)alloc((size_t)FIN * HD * 2);
    float* h           = (float*)alloc((size_t)N_NODES * HD * 4);
    float* el1         = (float*)alloc((size_t)N_NODES * 4 * 4);
    float* er1         = (float*)alloc((size_t)N_NODES * 4 * 4);
    float* feat2       = (float*)alloc((size_t)N_NODES * C2 * 4);
    float* el2         = (float*)alloc((size_t)N_NODES * 4);
    float* er2         = (float*)alloc((size_t)N_NODES * 4);
    int*   ghist       = (int*)alloc((size_t)NBUCK * NBLK * 4);
    int*   bucket_tot  = (int*)alloc((size_t)NBUCK * 4);
    int*   bucket_base = (int*)alloc((size_t)(NBUCK + 1) * 4);
    int*   rowstart    = (int*)alloc((size_t)(N_NODES + 1) * 4);
    int*   ebuf        = (int*)alloc((size_t)N_EDGES * 4);
    int*   sorted_src  = (int*)alloc((size_t)N_EDGES * 4);

    k_bhist<<<NBLK, 256, 0, stream>>>(dst, ghist);
    k_bscan1<<<NBUCK, 256, 0, stream>>>(ghist, bucket_tot);
    k_bscan2<<<1, 512, 0, stream>>>(bucket_tot, bucket_base, rowstart);
    k_bscatter<<<NBLK, 256, 0, stream>>>(src, dst, ghist, bucket_base, ebuf);
    k_bsort<<<NBUCK, 256, 0, stream>>>(ebuf, bucket_base, sorted_src, rowstart);
    k_w1half<<<128, 256, 0, stream>>>(W1, W1T);
    k_gemm1<<<(N_NODES + 63) / 64, 256, 0, stream>>>(x, W1T, al1, ar1, feath, el1, er1);
    k_agg1<<<(N_NODES * NHEADS) / 4, 256, 0, stream>>>(rowstart, sorted_src, el1, er1, feath, b1, h);
    k_gemm2<<<N_NODES / 16, 256, 0, stream>>>(h, W2, al2, ar2, feat2, el2, er2);
    k_agg2<<<N_NODES / 4, 256, 0, stream>>>(rowstart, sorted_src, el2, er2, feat2, b2, out);
}

// Round 12
// 246.585 us; speedup vs baseline: 1.1731x; 1.1731x over previous
//
#include <hip/hip_runtime.h>
#include <hip/hip_fp16.h>

#define N_NODES 50000
#define N_EDGES 1600000
#define FIN 256
#define HD 128          // HEADS*HIDDEN
#define NHEADS 4
#define C2 16           // NUM_CLASSES
#define NEG 0.2f

// bucketed counting-sort CSR build
#define EBLK 4096
#define NBLK 391        // ceil(N_EDGES/EBLK)
#define NBUCK 391       // ceil(N_NODES/128)
#define BSH 7
#define BMASK 127
#define MAXB 5120       // bucket capacity: mean 4096, sigma ~64 -> +16 sigma

typedef _Float16 v8h __attribute__((ext_vector_type(8)));
typedef float v4f __attribute__((ext_vector_type(4)));
union F4H8 { float4 f; v8h h; };

__device__ __forceinline__ float elu1(float x) { return x > 0.f ? x : __expf(x) - 1.f; }
__device__ __forceinline__ float lexp(float e) { return __expf(e > 0.f ? e : NEG * e); }

// ---------------- CSR build: bucketed counting sort ----------------

__global__ __launch_bounds__(256) void k_bhist(const int* __restrict__ dst,
                                               int* __restrict__ ghist) {
    __shared__ int lh[NBUCK];
    int tid = threadIdx.x, b = blockIdx.x;
    for (int t = tid; t < NBUCK; t += 256) lh[t] = 0;
    __syncthreads();
    int base = b * EBLK;
    int nq = (min(EBLK, N_EDGES - base)) >> 2;
    const int4* d4 = (const int4*)(dst + base);
    for (int q = tid; q < nq; q += 256) {
        int4 d = d4[q];
        atomicAdd(&lh[d.x >> BSH], 1);
        atomicAdd(&lh[d.y >> BSH], 1);
        atomicAdd(&lh[d.z >> BSH], 1);
        atomicAdd(&lh[d.w >> BSH], 1);
    }
    __syncthreads();
    for (int t = tid; t < NBUCK; t += 256) ghist[t * NBLK + b] = lh[t];
}

__global__ __launch_bounds__(256) void k_bscan1(int* __restrict__ ghist,
                                                int* __restrict__ bucket_tot) {
    __shared__ int s[256];
    int B = blockIdx.x, t = threadIdx.x;
    int* row = ghist + (size_t)B * NBLK;
    int i0 = 2 * t, i1 = 2 * t + 1;
    int a0 = (i0 < NBLK) ? row[i0] : 0;
    int a1 = (i1 < NBLK) ? row[i1] : 0;
    int pair = a0 + a1;
    s[t] = pair;
    __syncthreads();
    for (int off = 1; off < 256; off <<= 1) {
        int u = (t >= off) ? s[t - off] : 0;
        __syncthreads();
        s[t] += u;
        __syncthreads();
    }
    int excl = s[t] - pair;
    if (i0 < NBLK) row[i0] = excl;
    if (i1 < NBLK) row[i1] = excl + a0;
    if (t == 255) bucket_tot[B] = s[255];
}

__global__ __launch_bounds__(512) void k_bscan2(const int* __restrict__ bucket_tot,
                                                int* __restrict__ bucket_base,
                                                int* __restrict__ rowstart) {
    __shared__ int s[512];
    int t = threadIdx.x;
    int v = (t < NBUCK) ? bucket_tot[t] : 0;
    s[t] = v;
    __syncthreads();
    for (int off = 1; off < 512; off <<= 1) {
        int u = (t >= off) ? s[t - off] : 0;
        __syncthreads();
        s[t] += u;
        __syncthreads();
    }
    if (t < NBUCK) bucket_base[t] = s[t] - v;
    if (t == 0) { bucket_base[NBUCK] = N_EDGES; rowstart[N_NODES] = N_EDGES; }
}

__global__ __launch_bounds__(256) void k_bscatter(
        const int* __restrict__ src, const int* __restrict__ dst,
        const int* __restrict__ ghist, const int* __restrict__ bucket_base,
        int* __restrict__ ebuf) {
    __shared__ int lcur[NBUCK];
    int tid = threadIdx.x, b = blockIdx.x;
    for (int t = tid; t < NBUCK; t += 256)
        lcur[t] = bucket_base[t] + ghist[t * NBLK + b];
    __syncthreads();
    int base = b * EBLK;
    int nq = (min(EBLK, N_EDGES - base)) >> 2;
    const int4* s4 = (const int4*)(src + base);
    const int4* d4 = (const int4*)(dst + base);
    for (int q = tid; q < nq; q += 256) {
        int4 s = s4[q];
        int4 d = d4[q];
        int p;
        p = atomicAdd(&lcur[d.x >> BSH], 1); ebuf[p] = (s.x << BSH) | (d.x & BMASK);
        p = atomicAdd(&lcur[d.y >> BSH], 1); ebuf[p] = (s.y << BSH) | (d.y & BMASK);
        p = atomicAdd(&lcur[d.z >> BSH], 1); ebuf[p] = (s.z << BSH) | (d.z & BMASK);
        p = atomicAdd(&lcur[d.w >> BSH], 1); ebuf[p] = (s.w << BSH) | (d.w & BMASK);
    }
}

__global__ __launch_bounds__(256) void k_bsort(
        const int* __restrict__ ebuf, const int* __restrict__ bucket_base,
        int* __restrict__ sorted_src, int* __restrict__ rowstart) {
    __shared__ int ein[MAXB];
    __shared__ int eout[MAXB];
    __shared__ int hist[128];
    __shared__ int sc[128];
    __shared__ int cursor[128];
    int tid = threadIdx.x, B = blockIdx.x;
    int base = bucket_base[B];
    int n = bucket_base[B + 1] - base;
    if (tid < 128) hist[tid] = 0;
    __syncthreads();
    for (int i = tid; i < n; i += 256) {
        int v = ebuf[base + i];
        ein[i] = v;
        atomicAdd(&hist[v & BMASK], 1);
    }
    __syncthreads();
    if (tid < 128) sc[tid] = hist[tid];
    __syncthreads();
    for (int off = 1; off < 128; off <<= 1) {
        int u = 0;
        if (tid < 128 && tid >= off) u = sc[tid - off];
        __syncthreads();
        if (tid < 128) sc[tid] += u;
        __syncthreads();
    }
    if (tid < 128) {
        int ex = sc[tid] - hist[tid];
        cursor[tid] = ex;
        int node = B * 128 + tid;
        if (node < N_NODES) rowstart[node] = base + ex;
    }
    __syncthreads();
    for (int i = tid; i < n; i += 256) {
        int v = ein[i];
        int p = atomicAdd(&cursor[v & BMASK], 1);
        eout[p] = v >> BSH;
    }
    __syncthreads();
    for (int i = tid; i < n; i += 256) sorted_src[base + i] = eout[i];
}

// ---------------- W1 -> fp16 transposed [col][k] ----------------

__global__ __launch_bounds__(256) void k_w1half(const float* __restrict__ W1,
                                                _Float16* __restrict__ W1T) {
    int idx = blockIdx.x * 256 + threadIdx.x;   // 32768 total
    int k = idx >> 7, c = idx & 127;
    W1T[c * 256 + k] = (_Float16)W1[idx];
}

// ---------------- Layer 1 GEMM via MFMA fp16: feat1 = x @ W1, fused el1/er1 ----

__global__ __launch_bounds__(256) void k_gemm1(
        const float* __restrict__ x, const _Float16* __restrict__ W1T,
        const float* __restrict__ al1, const float* __restrict__ ar1,
        __half* __restrict__ feat1h, float* __restrict__ el1, float* __restrict__ er1) {
    __shared__ v8h As[64 * 4];    // 64 nodes x 32k fp16, 4 KB
    __shared__ v8h Bs[128 * 4];   // 128 cols x 32k fp16, 8 KB
    int tid = threadIdx.x;
    int nb = blockIdx.x * 64;
    int wid = tid >> 6, lane = tid & 63;
    int wm = wid & 1, wn = wid >> 1;      // wave tile: rows wm*32.., cols wn*64..
    int q = lane >> 4, lm = lane & 15;

    int anode = tid >> 2, ach = tid & 3;
    int gnode = nb + anode; if (gnode >= N_NODES) gnode = N_NODES - 1;
    const float4* xrow = (const float4*)(x + (size_t)gnode * FIN);
    int bc = tid >> 2, bch = tid & 3;

    v4f acc[2][4];
    #pragma unroll
    for (int mt = 0; mt < 2; mt++)
        #pragma unroll
        for (int nt = 0; nt < 4; nt++) acc[mt][nt] = (v4f)(0.f);

    float4 xa0 = xrow[ach * 2];
    float4 xa1 = xrow[ach * 2 + 1];
    F4H8 wb0, wb1;
    wb0.f = *(const float4*)(W1T + bc * 256 + bch * 8);
    wb1.f = *(const float4*)(W1T + (bc + 64) * 256 + bch * 8);

    for (int step = 0; step < 8; step++) {
        __syncthreads();
        {
            v8h av;
            av[0] = (_Float16)xa0.x; av[1] = (_Float16)xa0.y;
            av[2] = (_Float16)xa0.z; av[3] = (_Float16)xa0.w;
            av[4] = (_Float16)xa1.x; av[5] = (_Float16)xa1.y;
            av[6] = (_Float16)xa1.z; av[7] = (_Float16)xa1.w;
            As[anode * 4 + (ach ^ (anode & 3))] = av;
            Bs[bc * 4 + (bch ^ (bc & 3))] = wb0.h;
            Bs[(bc + 64) * 4 + (bch ^ (bc & 3))] = wb1.h;
        }
        __syncthreads();
        if (step < 7) {
            int k0 = (step + 1) * 32;
            xa0 = xrow[(k0 >> 2) + ach * 2];
            xa1 = xrow[(k0 >> 2) + ach * 2 + 1];
            wb0.f = *(const float4*)(W1T + bc * 256 + k0 + bch * 8);
            wb1.f = *(const float4*)(W1T + (bc + 64) * 256 + k0 + bch * 8);
        }
        v8h af[2], bf[4];
        #pragma unroll
        for (int mt = 0; mt < 2; mt++) {
            int nl = wm * 32 + mt * 16 + lm;
            af[mt] = As[nl * 4 + (q ^ (nl & 3))];
        }
        #pragma unroll
        for (int nt = 0; nt < 4; nt++) {
            int cl = wn * 64 + nt * 16 + lm;
            bf[nt] = Bs[cl * 4 + (q ^ (cl & 3))];
        }
        #pragma unroll
        for (int mt = 0; mt < 2; mt++)
            #pragma unroll
            for (int nt = 0; nt < 4; nt++)
                acc[mt][nt] = __builtin_amdgcn_mfma_f32_16x16x32_f16(
                    af[mt], bf[nt], acc[mt][nt], 0, 0, 0);
    }

    float alv[4], arv[4];
    #pragma unroll
    for (int nt = 0; nt < 4; nt++) {
        alv[nt] = al1[wn * 64 + nt * 16 + lm];
        arv[nt] = ar1[wn * 64 + nt * 16 + lm];
    }
    int h0 = 2 * wn, h1 = 2 * wn + 1;
    #pragma unroll
    for (int mt = 0; mt < 2; mt++) {
        #pragma unroll
        for (int r = 0; r < 4; r++) {
            int node = nb + wm * 32 + mt * 16 + q * 4 + r;
            bool ok = node < N_NODES;
            float v0 = acc[mt][0][r], v1 = acc[mt][1][r];
            float v2 = acc[mt][2][r], v3 = acc[mt][3][r];
            if (ok) {
                __half* fp = feat1h + (size_t)node * HD + wn * 64 + lm;
                fp[0]  = __float2half(v0);
                fp[16] = __float2half(v1);
                fp[32] = __float2half(v2);
                fp[48] = __float2half(v3);
            }
            float pl0 = v0 * alv[0] + v1 * alv[1];
            float pr0 = v0 * arv[0] + v1 * arv[1];
            float pl1 = v2 * alv[2] + v3 * alv[3];
            float pr1 = v2 * arv[2] + v3 * arv[3];
            #pragma unroll
            for (int m = 1; m <= 8; m <<= 1) {
                pl0 += __shfl_xor(pl0, m); pr0 += __shfl_xor(pr0, m);
                pl1 += __shfl_xor(pl1, m); pr1 += __shfl_xor(pr1, m);
            }
            if (ok && lm == 0) {
                el1[node * 4 + h0] = pl0; er1[node * 4 + h0] = pr0;
                el1[node * 4 + h1] = pl1; er1[node * 4 + h1] = pr1;
            }
        }
    }
}

// ---------------- Layer 1 aggregation: wave per dst, 16 edges in flight ----------------
// inner accumulation written element-wise over _Float16 to induce v_fma_mix_f32.

__global__ __launch_bounds__(256) void k_agg1(
        const int* __restrict__ rowstart, const int* __restrict__ sorted_src,
        const float* __restrict__ el1, const float* __restrict__ er1,
        const __half* __restrict__ feat1h, const float* __restrict__ b1,
        float* __restrict__ h) {
    int tid = threadIdx.x;
    int d = blockIdx.x * 4 + (tid >> 6);   // 50000 % 4 == 0
    int lane = tid & 63;
    int eg = lane >> 4;                    // edge group 0..3
    int cl = lane & 15;                    // col-lane: cols 8*cl..8*cl+7
    int head = cl >> 2;
    float er = er1[d * 4 + head];
    int start = rowstart[d], end = rowstart[d + 1];
    float acc[8];
    #pragma unroll
    for (int k = 0; k < 8; k++) acc[k] = 0.f;
    float wsum = 0.f;

    for (int i = start; i < end; i += 16) {
        int s[4]; bool ok[4];
        #pragma unroll
        for (int u = 0; u < 4; u++) {
            int e = i + 4 * u + eg;
            ok[u] = e < end;
            int ec = ok[u] ? e : end - 1;
            s[u] = sorted_src[ec];
        }
        float elv[4];
        #pragma unroll
        for (int u = 0; u < 4; u++) elv[u] = el1[s[u] * 4 + head];
        F4H8 r[4];
        #pragma unroll
        for (int u = 0; u < 4; u++)
            r[u].f = *(const float4*)(feat1h + (size_t)s[u] * HD + cl * 8);
        #pragma unroll
        for (int u = 0; u < 4; u++) {
            float w = ok[u] ? lexp(elv[u] + er) : 0.f;
            #pragma unroll
            for (int k = 0; k < 8; k++)
                acc[k] = fmaf((float)r[u].h[k], w, acc[k]);   // v_fma_mix_f32
            wsum += w;
        }
    }
    #pragma unroll
    for (int k = 0; k < 8; k++) {
        acc[k] += __shfl_xor(acc[k], 16);
        acc[k] += __shfl_xor(acc[k], 32);
    }
    wsum += __shfl_xor(wsum, 16);
    wsum += __shfl_xor(wsum, 32);
    if (eg == 0) {
        float inv = 1.f / fmaxf(wsum, 1e-9f);
        float v[8];
        #pragma unroll
        for (int k = 0; k < 8; k++) v[k] = elu1(acc[k] * inv + b1[cl * 8 + k]);
        float4* hp = (float4*)(h + (size_t)d * HD + cl * 8);
        hp[0] = make_float4(v[0], v[1], v[2], v[3]);
        hp[1] = make_float4(v[4], v[5], v[6], v[7]);
    }
}

// ---------------- Layer 2 GEMM: feat2 = h @ W2, fused el2/er2 ----------------

__global__ __launch_bounds__(256) void k_gemm2(
        const float* __restrict__ h, const float* __restrict__ W2,
        const float* __restrict__ al2, const float* __restrict__ ar2,
        float* __restrict__ feat2, float* __restrict__ el2, float* __restrict__ er2) {
    __shared__ float hs[16 * 132];
    __shared__ float w2t[16 * 132];
    int tid = threadIdx.x;
    int nb = blockIdx.x * 16;  // 50000 % 16 == 0
    for (int idx = tid; idx < 512; idx += 256) {
        int row = idx >> 5, kk = idx & 31;
        ((float4*)(hs + row * 132))[kk] = ((const float4*)h)[(size_t)(nb + row) * 32 + kk];
    }
    for (int idx = tid; idx < 2048; idx += 256) {
        int k = idx >> 4, c = idx & 15;
        w2t[c * 132 + k] = W2[idx];
    }
    __syncthreads();
    int nl = tid >> 4, col = tid & 15;
    const float4* hv = (const float4*)(hs + nl * 132);
    const float4* wv = (const float4*)(w2t + col * 132);
    float acc = 0.f;
    #pragma unroll
    for (int kk = 0; kk < 32; kk++) {
        float4 a = hv[kk], w = wv[kk];
        acc += a.x * w.x + a.y * w.y + a.z * w.z + a.w * w.w;
    }
    int node = nb + nl;
    feat2[node * 16 + col] = acc;
    float pl = acc * al2[col], pr = acc * ar2[col];
    #pragma unroll
    for (int m = 8; m >= 1; m >>= 1) {
        pl += __shfl_xor(pl, m);
        pr += __shfl_xor(pr, m);
    }
    if (col == 0) { el2[node] = pl; er2[node] = pr; }
}

// ---------------- Layer 2 aggregation: wave per dst, 16 edges x 4 col-lanes ----------------

__global__ __launch_bounds__(256) void k_agg2(
        const int* __restrict__ rowstart, const int* __restrict__ sorted_src,
        const float* __restrict__ el2, const float* __restrict__ er2,
        const float* __restrict__ feat2, const float* __restrict__ b2,
        float* __restrict__ out) {
    int tid = threadIdx.x;
    int d = blockIdx.x * 4 + (tid >> 6);   // 50000 % 4 == 0
    int lane = tid & 63;
    int eg = lane >> 2;                    // edge group 0..15
    int cq = lane & 3;                     // cols 4*cq..4*cq+3
    float er = er2[d];
    int start = rowstart[d], end = rowstart[d + 1];
    float4 acc = make_float4(0.f, 0.f, 0.f, 0.f);
    float wsum = 0.f;
    for (int i = start; i < end; i += 16) {
        int e = i + eg;
        bool ok = e < end;
        int ec = ok ? e : end - 1;
        int s = sorted_src[ec];
        float elv = el2[s];
        float4 f = ((const float4*)feat2)[(size_t)s * 4 + cq];
        float ev = elv + er;
        float wr = __expf(ev > 0.f ? ev : NEG * ev);
        float w = ok ? wr : 0.f;
        acc.x += w * f.x; acc.y += w * f.y; acc.z += w * f.z; acc.w += w * f.w;
        wsum += w;
    }
    #pragma unroll
    for (int m = 4; m <= 32; m <<= 1) {
        acc.x += __shfl_xor(acc.x, m);
        acc.y += __shfl_xor(acc.y, m);
        acc.z += __shfl_xor(acc.z, m);
        acc.w += __shfl_xor(acc.w, m);
        wsum  += __shfl_xor(wsum, m);
    }
    if (lane < 4) {
        float inv = 1.f / fmaxf(wsum, 1e-9f);
        float4 bv = ((const float4*)b2)[cq];
        float4 o = make_float4(acc.x * inv + bv.x, acc.y * inv + bv.y,
                               acc.z * inv + bv.z, acc.w * inv + bv.w);
        ((float4*)out)[(size_t)d * 4 + cq] = o;
    }
}

// ---------------- launch ----------------

extern "C" void kernel_launch(void* const* d_in, const int* in_sizes, int n_in,
                              void* d_out, int out_size, void* d_ws, size_t ws_size,
                              hipStream_t stream) {
    const float* x   = (const float*)d_in[0];
    const int*   src = (const int*)d_in[1];
    const int*   dst = (const int*)d_in[2];
    const float* W1  = (const float*)d_in[3];
    const float* b1  = (const float*)d_in[4];
    const float* al1 = (const float*)d_in[5];
    const float* ar1 = (const float*)d_in[6];
    const float* W2  = (const float*)d_in[7];
    const float* b2  = (const float*)d_in[8];
    const float* al2 = (const float*)d_in[9];
    const float* ar2 = (const float*)d_in[10];
    float* out = (float*)d_out;

    char* ws = (char*)d_ws;
    size_t off = 0;
    auto alloc = [&](size_t bytes) -> char* {
        char* p = ws + off;
        off += (bytes + 255) & ~(size_t)255;
        return p;
    };
    __half* feat1h     = (__half*)alloc((size_t)N_NODES * HD * 2);
    _Float16* W1T      = (_Float16*)alloc((size_t)FIN * HD * 2);
    float* h           = (float*)alloc((size_t)N_NODES * HD * 4);
    float* el1         = (float*)alloc((size_t)N_NODES * 4 * 4);
    float* er1         = (float*)alloc((size_t)N_NODES * 4 * 4);
    float* feat2       = (float*)alloc((size_t)N_NODES * C2 * 4);
    float* el2         = (float*)alloc((size_t)N_NODES * 4);
    float* er2         = (float*)alloc((size_t)N_NODES * 4);
    int*   ghist       = (int*)alloc((size_t)NBUCK * NBLK * 4);
    int*   bucket_tot  = (int*)alloc((size_t)NBUCK * 4);
    int*   bucket_base = (int*)alloc((size_t)(NBUCK + 1) * 4);
    int*   rowstart    = (int*)alloc((size_t)(N_NODES + 1) * 4);
    int*   ebuf        = (int*)alloc((size_t)N_EDGES * 4);
    int*   sorted_src  = (int*)alloc((size_t)N_EDGES * 4);

    k_bhist<<<NBLK, 256, 0, stream>>>(dst, ghist);
    k_bscan1<<<NBUCK, 256, 0, stream>>>(ghist, bucket_tot);
    k_bscan2<<<1, 512, 0, stream>>>(bucket_tot, bucket_base, rowstart);
    k_bscatter<<<NBLK, 256, 0, stream>>>(src, dst, ghist, bucket_base, ebuf);
    k_bsort<<<NBUCK, 256, 0, stream>>>(ebuf, bucket_base, sorted_src, rowstart);
    k_w1half<<<128, 256, 0, stream>>>(W1, W1T);
    k_gemm1<<<(N_NODES + 63) / 64, 256, 0, stream>>>(x, W1T, al1, ar1, feat1h, el1, er1);
    k_agg1<<<N_NODES / 4, 256, 0, stream>>>(rowstart, sorted_src, el1, er1, feat1h, b1, h);
    k_gemm2<<<N_NODES / 16, 256, 0, stream>>>(h, W2, al2, ar2, feat2, el2, er2);
    k_agg2<<<N_NODES / 4, 256, 0, stream>>>(rowstart, sorted_src, el2, er2, feat2, b2, out);
}